// Round 9
// baseline (104.268 us; speedup 1.0000x reference)
//
#include <hip/hip_runtime.h>
#include <hip/hip_bf16.h>

#define N_NODES  12288
#define N_FEAT   256
#define KDIM     128
#define N_GRAPHS 192
#define NMAX     112          // LDS fast-path max graph size (mean 64, std ~8)
#define KSTR     68           // Ks row stride u32 (272 B, 16B-aligned b128; 4 mod 32 -> free)
#define QSTR     66           // Qs row stride u32 (264 B, 8B-aligned b64; 2 mod 32 -> free)

// workspace layout (bytes)
#define WS_STARTS 0
#define WS_WGLOB  1024                                  // fp32 w [12288] (slow path)
#define WS_QSLOW  (WS_WGLOB + N_NODES * 4)              // fp32 Qslow [12288][128] (slow path)
#define WS_KSLOW  (WS_QSLOW + N_NODES * KDIM * 4)       // fp32 Kslow (slow path)
#define WS_WT     (WS_KSLOW + N_NODES * KDIM * 4)       // bf16 Wt [256][256] as u32[128]

typedef __bf16 bf16x8 __attribute__((ext_vector_type(8)));
typedef float  f32x4  __attribute__((ext_vector_type(4)));

union U8 { unsigned u[4]; bf16x8 v; };

__device__ __forceinline__ unsigned bf16_rne(float f) {
  unsigned u = __float_as_uint(f);
  return (u + 0x7FFFu + ((u >> 16) & 1u)) >> 16;
}
__device__ __forceinline__ unsigned pack_bf16(float lo, float hi) {
  return bf16_rne(lo) | (bf16_rne(hi) << 16);
}

// ---------------------------------------------------------------------------
// Kernel 1: W pre-transpose to bf16 (Wt[n][k]: n<128 -> Wq col n, n>=128 ->
// Wk col n-128) + segment starts via binary search (batch sorted).
// ---------------------------------------------------------------------------
__global__ __launch_bounds__(64) void wt_prep_k(const float* __restrict__ Wq,
                                                const float* __restrict__ Wk,
                                                const int* __restrict__ batch,
                                                unsigned* __restrict__ Wt,
                                                int* __restrict__ starts) {
  const int n = blockIdx.x;
  const int t = threadIdx.x;
  const float* src = (n < KDIM) ? (Wq + n) : (Wk + (n - KDIM));
  float f0 = src[(4 * t + 0) * KDIM];
  float f1 = src[(4 * t + 1) * KDIM];
  float f2 = src[(4 * t + 2) * KDIM];
  float f3 = src[(4 * t + 3) * KDIM];
  Wt[n * 128 + 2 * t]     = pack_bf16(f0, f1);
  Wt[n * 128 + 2 * t + 1] = pack_bf16(f2, f3);

  if (t == 0 && n <= N_GRAPHS) {
    int lo = 0, hi = N_NODES;
    while (lo < hi) {
      int mid = (lo + hi) >> 1;
      if (batch[mid] < n) lo = mid + 1; else hi = mid;
    }
    starts[n] = lo;
  }
}

// ---------------------------------------------------------------------------
// Kernel 2: fully-fused per-graph attention pooling. One 512-thr block/graph.
// Fast path (n <= 112):
//   Phase P: wave s projects strip s: A = X rows (fp32->bf16 in-reg), B = Wt
//     (global, L2-hot). 8 kq-steps x 8 n-tiles x {Q,K} = 128 MFMA/wave.
//     C-frags -> LDS: Qs (scale 1/16, stride 66) + Ks (stride 68), bf16.
//   Phase S: scores via MFMA (A from Qs b64, B from Ks b128), in-wave softmax
//     (quad shfl), column weights -> w_lds -> w.
//   Phase U: u[f] = sum_j w[j] X[i0+j][f]; out[g] = u @ Wv. All in-block.
// Slow path (n > 112): fp32 Q/K into private global scratch, two-pass online
// softmax -> wglob (one block/graph: race-free), same U/out tail.
// ---------------------------------------------------------------------------
__global__ __launch_bounds__(512) void attn_fused_k(const float* __restrict__ X,
                                                    const int* __restrict__ starts,
                                                    const unsigned* __restrict__ Wt,
                                                    const float* __restrict__ Wq,
                                                    const float* __restrict__ Wk,
                                                    const float* __restrict__ Wv,
                                                    float* __restrict__ out,
                                                    float* __restrict__ wglob,
                                                    float* __restrict__ Qslow,
                                                    float* __restrict__ Kslow) {
  __shared__ unsigned Ks_u[NMAX * KSTR];   // 30464 B
  __shared__ unsigned Qs_u[NMAX * QSTR];   // 29568 B
  __shared__ float    w_lds[7][NMAX];      // 3136 B (ns <= 7; also out-partial scratch)
  __shared__ float    red[2][256];         // 2048 B     -> total 65216 B

  const int tid  = threadIdx.x;
  const int lane = tid & 63;
  const int wv   = tid >> 6;
  const int l15  = lane & 15;
  const int quad = lane >> 4;
  const int g    = blockIdx.x;

  const int i0 = starts[g];
  const int n  = starts[g + 1] - i0;
  const float BIG = 1e30f;
  const bool fast = (n <= NMAX);

  if (fast) {
    const int ns = (n + 15) >> 4;   // strips; wave s handles strip s (ns <= 7)

    // ================= Phase P: in-block Q/K projection =================
    if (wv < ns) {
      const int s = wv;
      const int arow = i0 + min(s * 16 + l15, n - 1);
      f32x4 accq[8], acck[8];
#pragma unroll
      for (int nt = 0; nt < 8; nt++) {
        accq[nt] = (f32x4){0.f, 0.f, 0.f, 0.f};
        acck[nt] = (f32x4){0.f, 0.f, 0.f, 0.f};
      }
#pragma unroll
      for (int ks = 0; ks < 8; ks++) {
        // A-frag: X[arow][ks*32 + quad*8 ..+7] fp32 -> bf16x8
        const float* xp = &X[(size_t)arow * N_FEAT + ks * 32 + quad * 8];
        float4 xa = *(const float4*)xp;
        float4 xb = *(const float4*)(xp + 4);
        U8 t;
        t.u[0] = pack_bf16(xa.x, xa.y); t.u[1] = pack_bf16(xa.z, xa.w);
        t.u[2] = pack_bf16(xb.x, xb.y); t.u[3] = pack_bf16(xb.z, xb.w);
        bf16x8 a = t.v;
#pragma unroll
        for (int nt = 0; nt < 8; nt++) {
          bf16x8 bq = *(const bf16x8*)&Wt[(size_t)(nt * 16 + l15) * 128 + ks * 16 + quad * 4];
          bf16x8 bk = *(const bf16x8*)&Wt[(size_t)(128 + nt * 16 + l15) * 128 + ks * 16 + quad * 4];
          accq[nt] = __builtin_amdgcn_mfma_f32_16x16x32_bf16(a, bq, accq[nt], 0, 0, 0);
          acck[nt] = __builtin_amdgcn_mfma_f32_16x16x32_bf16(a, bk, acck[nt], 0, 0, 0);
        }
      }
      // epilogue: C col = kdim (nt*16+l15), row = node (s*16+quad*4+e) -> LDS bf16
#pragma unroll
      for (int nt = 0; nt < 8; nt++) {
        const int c = nt * 16 + l15;
#pragma unroll
        for (int e = 0; e < 4; e++) {
          const int r = s * 16 + quad * 4 + e;   // local node row, < 112
          unsigned bq = bf16_rne(accq[nt][e] * 0.0625f);
          unsigned bk = bf16_rne(acck[nt][e]);
          unsigned bqp = __shfl_xor((int)bq, 1);
          unsigned bkp = __shfl_xor((int)bk, 1);
          if ((lane & 1) == 0) {
            Qs_u[r * QSTR + (c >> 1)] = bq | (bqp << 16);
            Ks_u[r * KSTR + (c >> 1)] = bk | (bkp << 16);
          }
        }
      }
    }
    __syncthreads();

    // ================= Phase S: scores + softmax + column weights ========
    float wl[7];
#pragma unroll
    for (int f = 0; f < 7; f++) wl[f] = 0.f;

    if (wv < ns) {
      const int s = wv;
      bf16x8 au[4];
#pragma unroll
      for (int ks = 0; ks < 4; ks++) {   // A from Qs (b64 pair: stride 66 u32)
        U8 t;
        const unsigned* qp = &Qs_u[(s * 16 + l15) * QSTR + ks * 16 + quad * 4];
        *(uint2*)&t.u[0] = *(const uint2*)qp;
        *(uint2*)&t.u[2] = *(const uint2*)(qp + 2);
        au[ks] = t.v;
      }
      f32x4 acc[7];
#pragma unroll
      for (int f = 0; f < 7; f++) acc[f] = (f32x4){0.f, 0.f, 0.f, 0.f};
#pragma unroll
      for (int f = 0; f < 7; f++) {
#pragma unroll
        for (int ks = 0; ks < 4; ks++) {
          bf16x8 bu = *(const bf16x8*)&Ks_u[(f * 16 + l15) * KSTR + ks * 16 + quad * 4];
          acc[f] = __builtin_amdgcn_mfma_f32_16x16x32_bf16(au[ks], bu, acc[f], 0, 0, 0);
        }
      }
#pragma unroll
      for (int f = 0; f < 7; f++)
        if (f * 16 + l15 >= n) {
          acc[f][0] = -BIG; acc[f][1] = -BIG; acc[f][2] = -BIG; acc[f][3] = -BIG;
        }
#pragma unroll
      for (int e = 0; e < 4; e++) {
        float m = -BIG;
#pragma unroll
        for (int f = 0; f < 7; f++) m = fmaxf(m, acc[f][e]);
        m = fmaxf(m, __shfl_xor(m, 1));
        m = fmaxf(m, __shfl_xor(m, 2));
        m = fmaxf(m, __shfl_xor(m, 4));
        m = fmaxf(m, __shfl_xor(m, 8));
        float p[7], l = 0.f;
#pragma unroll
        for (int f = 0; f < 7; f++) { p[f] = __expf(acc[f][e] - m); l += p[f]; }
        l += __shfl_xor(l, 1);
        l += __shfl_xor(l, 2);
        l += __shfl_xor(l, 4);
        l += __shfl_xor(l, 8);
        const int row = s * 16 + quad * 4 + e;
        float inv = (row < n) ? (1.f / l) : 0.f;
#pragma unroll
        for (int f = 0; f < 7; f++) wl[f] = fmaf(p[f], inv, wl[f]);
      }
    }
#pragma unroll
    for (int f = 0; f < 7; f++) {
      wl[f] += __shfl_xor(wl[f], 16);
      wl[f] += __shfl_xor(wl[f], 32);
    }
    if (wv < 7 && lane < 16) {
#pragma unroll
      for (int f = 0; f < 7; f++) w_lds[wv][f * 16 + lane] = wl[f];
    }
    __syncthreads();

    if (tid < NMAX) {
      float t = 0.f;
#pragma unroll
      for (int k = 0; k < 7; k++) t += w_lds[k][tid];
      w_lds[0][tid] = t;
    }
    __syncthreads();
  } else {
    // ================= slow path (n > 112; backstop) ====================
    for (int idx = tid; idx < n; idx += 512) wglob[i0 + idx] = 0.f;
    __syncthreads();
    // fp32 Q/K into private global scratch (scale folded into Q)
    for (int r = tid >> 7; r < n; r += 4) {
      const int kd = tid & 127;
      const float* xr = &X[(size_t)(i0 + r) * N_FEAT];
      float aq = 0.f, ak = 0.f;
      for (int k = 0; k < N_FEAT; k++) {
        float xv = xr[k];
        aq = fmaf(xv, Wq[k * KDIM + kd], aq);
        ak = fmaf(xv, Wk[k * KDIM + kd], ak);
      }
      Qslow[(size_t)(i0 + r) * KDIM + kd] = aq * 0.0625f;
      Kslow[(size_t)(i0 + r) * KDIM + kd] = ak;
    }
    __threadfence();
    __syncthreads();
    for (int lr = wv; lr < n; lr += 8) {
      const float* qp = &Qslow[(size_t)(i0 + lr) * KDIM];
      float m_run = -BIG, l_run = 0.f;
      for (int jb = 0; jb < n; jb += 64) {
        int j = jb + lane;
        int jc = min(j, n - 1);
        const float* kp = &Kslow[(size_t)(i0 + jc) * KDIM];
        float s = 0.f;
        for (int k = 0; k < KDIM; k++) s = fmaf(qp[k], kp[k], s);
        if (j >= n) s = -BIG;
        float mc = s;
        for (int off = 32; off; off >>= 1) mc = fmaxf(mc, __shfl_xor(mc, off));
        float m_new = fmaxf(m_run, mc);
        float lc = __expf(s - m_new);
        for (int off = 32; off; off >>= 1) lc += __shfl_xor(lc, off);
        l_run = l_run * __expf(m_run - m_new) + lc;
        m_run = m_new;
      }
      float inv = 1.f / l_run;
      for (int jb = 0; jb < n; jb += 64) {
        int j = jb + lane;
        int jc = min(j, n - 1);
        const float* kp = &Kslow[(size_t)(i0 + jc) * KDIM];
        float s = 0.f;
        for (int k = 0; k < KDIM; k++) s = fmaf(qp[k], kp[k], s);
        if (j < n) atomicAdd(&wglob[i0 + j], __expf(s - m_run) * inv);
      }
    }
    __threadfence();
    __syncthreads();
  }

  // ================= Phase U: u = w^T X ; out = u @ Wv ==================
  const int f  = tid & 255;
  const int jp = tid >> 8;
  float ua = 0.f, ub = 0.f;
  if (fast) {
    int j = jp;
    for (; j + 2 < n; j += 4) {
      ua = fmaf(w_lds[0][j],     X[(size_t)(i0 + j) * N_FEAT + f], ua);
      ub = fmaf(w_lds[0][j + 2], X[(size_t)(i0 + j + 2) * N_FEAT + f], ub);
    }
    for (; j < n; j += 2)
      ua = fmaf(w_lds[0][j], X[(size_t)(i0 + j) * N_FEAT + f], ua);
  } else {
    for (int j = jp; j < n; j += 2) {
      float wj = atomicAdd(&wglob[i0 + j], 0.f);   // coherent read
      ua = fmaf(wj, X[(size_t)(i0 + j) * N_FEAT + f], ua);
    }
  }
  red[jp][f] = ua + ub;
  __syncthreads();
  if (jp == 0) red[0][f] += red[1][f];   // red[0] = u
  __syncthreads();

  const int k0 = jp * 128;
  const float* wp = Wv + (size_t)k0 * N_FEAT + f;
  const float* us = &red[0][k0];
  float a0 = 0.f, a1 = 0.f, a2 = 0.f, a3 = 0.f;
#pragma unroll 8
  for (int k = 0; k < 128; k += 4) {
    a0 = fmaf(us[k],     wp[(size_t)k * N_FEAT], a0);
    a1 = fmaf(us[k + 1], wp[(size_t)(k + 1) * N_FEAT], a1);
    a2 = fmaf(us[k + 2], wp[(size_t)(k + 2) * N_FEAT], a2);
    a3 = fmaf(us[k + 3], wp[(size_t)(k + 3) * N_FEAT], a3);
  }
  float* op = (float*)w_lds;   // reuse (w no longer needed)
  __syncthreads();
  op[jp * 256 + f] = (a0 + a1) + (a2 + a3);
  __syncthreads();
  if (jp == 0) out[g * N_FEAT + f] = op[f] + op[256 + f];
}

// ---------------------------------------------------------------------------
extern "C" void kernel_launch(void* const* d_in, const int* in_sizes, int n_in,
                              void* d_out, int out_size, void* d_ws, size_t ws_size,
                              hipStream_t stream) {
  const float* X     = (const float*)d_in[0];
  const int*   batch = (const int*)d_in[1];
  const float* Wq    = (const float*)d_in[2];
  const float* Wk    = (const float*)d_in[3];
  const float* Wv    = (const float*)d_in[4];
  float* out = (float*)d_out;

  char* ws = (char*)d_ws;
  int*      starts = (int*)(ws + WS_STARTS);
  float*    wglob  = (float*)(ws + WS_WGLOB);
  float*    Qslow  = (float*)(ws + WS_QSLOW);
  float*    Kslow  = (float*)(ws + WS_KSLOW);
  unsigned* Wt     = (unsigned*)(ws + WS_WT);

  wt_prep_k<<<256, 64, 0, stream>>>(Wq, Wk, batch, Wt, starts);
  attn_fused_k<<<N_GRAPHS, 512, 0, stream>>>(X, starts, Wt, Wq, Wk, Wv,
                                             out, wglob, Qslow, Kslow);
}

// Round 10
// 97.919 us; speedup vs baseline: 1.0648x; 1.0648x over previous
//
#include <hip/hip_runtime.h>
#include <hip/hip_bf16.h>

#define N_NODES  12288
#define N_FEAT   256
#define KDIM     128
#define N_GRAPHS 192
#define NMAX     112          // LDS fast-path max graph size (mean 64, std ~8)
#define KSTRIDE_U 68          // K LDS row stride in u32 (272 B; 4j mod 32 -> 2-way=free)
#define XS_STRIDE_U 132       // X LDS row stride in u32 (132%32=4 -> 2-way=free; 16B-aligned)

// workspace layout (bytes)
#define WS_STARTS 0
#define WS_WBUF   1024                                  // fp32 w [12288] (slow path only)
#define WS_QB     (WS_WBUF + N_NODES * 4)               // bf16 Q [12288][128] as u32[64]
#define WS_KB     (WS_QB + N_NODES * 64 * 4)            // bf16 K [12288][128] as u32[64]
#define WS_WT     (WS_KB + N_NODES * 64 * 4)            // bf16 Wt [256][256] as u32[128]

typedef __bf16 bf16x8 __attribute__((ext_vector_type(8)));
typedef float  f32x4  __attribute__((ext_vector_type(4)));

__device__ __forceinline__ unsigned bf16_rne(float f) {
  unsigned u = __float_as_uint(f);
  return (u + 0x7FFFu + ((u >> 16) & 1u)) >> 16;
}
__device__ __forceinline__ unsigned pack_bf16(float lo, float hi) {
  return bf16_rne(lo) | (bf16_rne(hi) << 16);
}
__device__ __forceinline__ float bf_lo(unsigned u) { return __uint_as_float(u << 16); }
__device__ __forceinline__ float bf_hi(unsigned u) { return __uint_as_float(u & 0xFFFF0000u); }

// ---------------------------------------------------------------------------
// Kernel 1: W pre-transpose to bf16 (Wt[n][k], packed u32 pairs) + segment
// starts (block n <= 192: starts[n] = lower_bound(batch, n); batch sorted).
// ---------------------------------------------------------------------------
__global__ __launch_bounds__(64) void wt_prep_k(const float* __restrict__ Wq,
                                                const float* __restrict__ Wk,
                                                const int* __restrict__ batch,
                                                unsigned* __restrict__ Wt,
                                                int* __restrict__ starts) {
  const int n = blockIdx.x;
  const int t = threadIdx.x;
  const float* src = (n < KDIM) ? (Wq + n) : (Wk + (n - KDIM));
  float f0 = src[(4 * t + 0) * KDIM];
  float f1 = src[(4 * t + 1) * KDIM];
  float f2 = src[(4 * t + 2) * KDIM];
  float f3 = src[(4 * t + 3) * KDIM];
  Wt[n * 128 + 2 * t]     = pack_bf16(f0, f1);
  Wt[n * 128 + 2 * t + 1] = pack_bf16(f2, f3);

  if (t == 0 && n <= N_GRAPHS) {
    int lo = 0, hi = N_NODES;
    while (lo < hi) {
      int mid = (lo + hi) >> 1;
      if (batch[mid] < n) lo = mid + 1; else hi = mid;
    }
    starts[n] = lo;
  }
}

// ---------------------------------------------------------------------------
// Kernel 2: fused Q|K projection via bf16 MFMA. M-tile 16 -> 768 blocks x
// 256 thr. X staged once (full K=256, 8.5 KB LDS, ONE barrier); W B-frags
// read directly from global Wt (128 KB, L2-resident; each frag = 16 rows x
// 64 contiguous bytes). Wave wv owns cols 64wv..64wv+63: waves 0-1 -> Q
// (scaled 1/16), 2-3 -> K. Both outputs packed bf16.
// ---------------------------------------------------------------------------
__global__ __launch_bounds__(256) void qk_proj_k(const float* __restrict__ X,
                                                 const unsigned* __restrict__ Wt,
                                                 unsigned* __restrict__ Qb,
                                                 unsigned* __restrict__ Kb) {
  __shared__ unsigned Xs_u[16 * XS_STRIDE_U];   // 8448 B

  const int tid  = threadIdx.x;
  const int lane = tid & 63;
  const int wv   = tid >> 6;
  const int r0   = blockIdx.x * 16;
  const int l15  = lane & 15;
  const int quad = lane >> 4;

  // ---- stage X tile: 16 rows x 256 k, fp32 -> bf16, one shot ----
  {
    const int row = tid >> 4, seg = tid & 15;   // 8 u32 (16 bf16) per thread
    const float* xp = &X[(size_t)(r0 + row) * N_FEAT + seg * 16];
    float4 a = *(const float4*)xp;
    float4 b = *(const float4*)(xp + 4);
    float4 c = *(const float4*)(xp + 8);
    float4 d = *(const float4*)(xp + 12);
    unsigned* dst = &Xs_u[row * XS_STRIDE_U + seg * 8];
    *(uint4*)dst       = make_uint4(pack_bf16(a.x, a.y), pack_bf16(a.z, a.w),
                                    pack_bf16(b.x, b.y), pack_bf16(b.z, b.w));
    *(uint4*)(dst + 4) = make_uint4(pack_bf16(c.x, c.y), pack_bf16(c.z, c.w),
                                    pack_bf16(d.x, d.y), pack_bf16(d.z, d.w));
  }
  __syncthreads();

  f32x4 acc[4];
#pragma unroll
  for (int ni = 0; ni < 4; ni++) acc[ni] = (f32x4){0.f, 0.f, 0.f, 0.f};

#pragma unroll
  for (int ks = 0; ks < 8; ks++) {
    bf16x8 a = *(const bf16x8*)&Xs_u[l15 * XS_STRIDE_U + ks * 16 + quad * 4];
    bf16x8 b[4];
#pragma unroll
    for (int ni = 0; ni < 4; ni++)
      b[ni] = *(const bf16x8*)&Wt[(size_t)(wv * 64 + ni * 16 + l15) * 128 + ks * 16 + quad * 4];
#pragma unroll
    for (int ni = 0; ni < 4; ni++)
      acc[ni] = __builtin_amdgcn_mfma_f32_16x16x32_bf16(a, b[ni], acc[ni], 0, 0, 0);
  }

  // ---- epilogue: C/D col = lane&15, row = quad*4 + e; pack bf16 pairs ----
  unsigned* dst = (wv < 2) ? Qb : Kb;
  const float scale = (wv < 2) ? 0.0625f : 1.0f;
  const int colbase = (wv & 1) * 64;
#pragma unroll
  for (int ni = 0; ni < 4; ni++) {
    const int col = colbase + ni * 16 + l15;
#pragma unroll
    for (int e = 0; e < 4; e++) {
      const int row = r0 + quad * 4 + e;
      unsigned b = bf16_rne(acc[ni][e] * scale);
      unsigned partner = __shfl_xor((int)b, 1);
      if ((lane & 1) == 0)
        dst[row * 64 + (col >> 1)] = b | (partner << 16);
    }
  }
}

// ---------------------------------------------------------------------------
// Kernel 3: fused attention pooling — one 512-thr block (8 waves) per graph.
// Phase A: stage K tile (bf16, stride-68) -> wave s computes 16-row strip s
//   (7 col-groups x 4 k-steps = 28 MFMA) -> in-wave softmax (quad shfl) ->
//   column weights reduced shfl{16,32} -> w_lds.
// Phase B: w2 = sum over waves; u[f] = sum_j w2[j] X[i0+j][f] (2-way j-split);
//   out[g] = u @ Wv (2-way k-split). All in-block, no atomics, no memset.
// Slow path (n > NMAX): block zeroes its own wbuf segment, two-pass online
// softmax into wbuf via atomics (single block per graph -> race-free).
// ---------------------------------------------------------------------------
__global__ __launch_bounds__(512) void attn_pool_k(const float* __restrict__ X,
                                                   const int* __restrict__ starts,
                                                   const unsigned* __restrict__ Qb,
                                                   const unsigned* __restrict__ Kb,
                                                   const float* __restrict__ Wv,
                                                   float* __restrict__ out,
                                                   float* __restrict__ wbuf) {
  __shared__ unsigned Ks_u[NMAX * KSTRIDE_U];   // 30464 B
  __shared__ float    w_lds[8][NMAX];           // 3584 B
  __shared__ float    red[2][256];              // 2048 B
  __shared__ float    Us[256];                  // 1024 B

  const int tid  = threadIdx.x;
  const int lane = tid & 63;
  const int wv   = tid >> 6;
  const int l15  = lane & 15;
  const int quad = lane >> 4;
  const int g    = blockIdx.x;

  const int i0 = starts[g];
  const int n  = starts[g + 1] - i0;
  const float BIG = 1e30f;
  const bool fast = (n <= NMAX);

  if (fast) {
    // ---- stage K tile ----
    for (int idx = tid; idx < n * 16; idx += 512) {
      int j = idx >> 4, c = idx & 15;
      *(uint4*)&Ks_u[j * KSTRIDE_U + 4 * c] = *(const uint4*)&Kb[(size_t)(i0 + j) * 64 + 4 * c];
    }
    __syncthreads();

    float wl[7];
#pragma unroll
    for (int f = 0; f < 7; f++) wl[f] = 0.f;

    const int ns = (n + 15) >> 4;   // strips; wave s handles strip s
    if (wv < ns) {
      const int s = wv;
      const int arow = min(s * 16 + l15, n - 1);
      const unsigned* qrow = &Qb[(size_t)(i0 + arow) * 64];
      bf16x8 au[4];
#pragma unroll
      for (int ks = 0; ks < 4; ks++)
        au[ks] = *(const bf16x8*)&qrow[ks * 16 + quad * 4];

      f32x4 acc[7];
#pragma unroll
      for (int f = 0; f < 7; f++) acc[f] = (f32x4){0.f, 0.f, 0.f, 0.f};
#pragma unroll
      for (int f = 0; f < 7; f++) {
#pragma unroll
        for (int ks = 0; ks < 4; ks++) {
          bf16x8 bu = *(const bf16x8*)&Ks_u[(f * 16 + l15) * KSTRIDE_U + ks * 16 + quad * 4];
          acc[f] = __builtin_amdgcn_mfma_f32_16x16x32_bf16(au[ks], bu, acc[f], 0, 0, 0);
        }
      }
#pragma unroll
      for (int f = 0; f < 7; f++)
        if (f * 16 + l15 >= n) {
          acc[f][0] = -BIG; acc[f][1] = -BIG; acc[f][2] = -BIG; acc[f][3] = -BIG;
        }

#pragma unroll
      for (int e = 0; e < 4; e++) {
        float m = -BIG;
#pragma unroll
        for (int f = 0; f < 7; f++) m = fmaxf(m, acc[f][e]);
        m = fmaxf(m, __shfl_xor(m, 1));
        m = fmaxf(m, __shfl_xor(m, 2));
        m = fmaxf(m, __shfl_xor(m, 4));
        m = fmaxf(m, __shfl_xor(m, 8));
        float p[7], l = 0.f;
#pragma unroll
        for (int f = 0; f < 7; f++) { p[f] = __expf(acc[f][e] - m); l += p[f]; }
        l += __shfl_xor(l, 1);
        l += __shfl_xor(l, 2);
        l += __shfl_xor(l, 4);
        l += __shfl_xor(l, 8);
        const int row = s * 16 + quad * 4 + e;
        float inv = (row < n) ? (1.f / l) : 0.f;
#pragma unroll
        for (int f = 0; f < 7; f++) wl[f] = fmaf(p[f], inv, wl[f]);
      }
    }

    // ---- reduce across quads (column j = f*16 + l15) ----
#pragma unroll
    for (int f = 0; f < 7; f++) {
      wl[f] += __shfl_xor(wl[f], 16);
      wl[f] += __shfl_xor(wl[f], 32);
    }
    if (lane < 16) {
#pragma unroll
      for (int f = 0; f < 7; f++) w_lds[wv][f * 16 + lane] = wl[f];
    }
    __syncthreads();

    // ---- w2[j] = sum over 8 waves ----
    if (tid < NMAX) {
      float t = 0.f;
#pragma unroll
      for (int k = 0; k < 8; k++) t += w_lds[k][tid];
      w_lds[0][tid] = t;
    }
    __syncthreads();
  } else {
    // ---- slow path: zero own wbuf segment, two-pass online softmax ----
    for (int idx = tid; idx < n; idx += 512) wbuf[i0 + idx] = 0.f;
    __syncthreads();
    for (int lr = wv; lr < n; lr += 8) {
      const uint4* qp4 = (const uint4*)&Qb[(size_t)(i0 + lr) * 64];
      float m_run = -BIG, l_run = 0.f;
      for (int jb = 0; jb < n; jb += 64) {
        int j = jb + lane;
        int jc = min(j, n - 1);
        const uint4* kp4 = (const uint4*)&Kb[(size_t)(i0 + jc) * 64];
        float s = 0.f;
        for (int c = 0; c < 16; c++) {
          uint4 Q1 = qp4[c];
          uint4 K1 = kp4[c];
          s = fmaf(bf_lo(Q1.x), bf_lo(K1.x), s); s = fmaf(bf_hi(Q1.x), bf_hi(K1.x), s);
          s = fmaf(bf_lo(Q1.y), bf_lo(K1.y), s); s = fmaf(bf_hi(Q1.y), bf_hi(K1.y), s);
          s = fmaf(bf_lo(Q1.z), bf_lo(K1.z), s); s = fmaf(bf_hi(Q1.z), bf_hi(K1.z), s);
          s = fmaf(bf_lo(Q1.w), bf_lo(K1.w), s); s = fmaf(bf_hi(Q1.w), bf_hi(K1.w), s);
        }
        if (j >= n) s = -BIG;
        float mc = s;
        for (int off = 32; off; off >>= 1) mc = fmaxf(mc, __shfl_xor(mc, off));
        float m_new = fmaxf(m_run, mc);
        float lc = __expf(s - m_new);
        for (int off = 32; off; off >>= 1) lc += __shfl_xor(lc, off);
        l_run = l_run * __expf(m_run - m_new) + lc;
        m_run = m_new;
      }
      float inv = 1.f / l_run;
      for (int jb = 0; jb < n; jb += 64) {
        int j = jb + lane;
        int jc = min(j, n - 1);
        const uint4* kp4 = (const uint4*)&Kb[(size_t)(i0 + jc) * 64];
        float s = 0.f;
        for (int c = 0; c < 16; c++) {
          uint4 Q1 = qp4[c];
          uint4 K1 = kp4[c];
          s = fmaf(bf_lo(Q1.x), bf_lo(K1.x), s); s = fmaf(bf_hi(Q1.x), bf_hi(K1.x), s);
          s = fmaf(bf_lo(Q1.y), bf_lo(K1.y), s); s = fmaf(bf_hi(Q1.y), bf_hi(K1.y), s);
          s = fmaf(bf_lo(Q1.z), bf_lo(K1.z), s); s = fmaf(bf_hi(Q1.z), bf_hi(K1.z), s);
          s = fmaf(bf_lo(Q1.w), bf_lo(K1.w), s); s = fmaf(bf_hi(Q1.w), bf_hi(K1.w), s);
        }
        if (j < n) atomicAdd(&wbuf[i0 + j], __expf(s - m_run) * inv);
      }
    }
    __threadfence();
    __syncthreads();
  }

  // ---- u[f] = sum_j w[j] * X[i0+j][f]  (2-way j-split) ----
  const int f  = tid & 255;
  const int jp = tid >> 8;
  float ua = 0.f, ub = 0.f;
  if (fast) {
    int j = jp;
    for (; j + 2 < n; j += 4) {
      ua = fmaf(w_lds[0][j],     X[(size_t)(i0 + j) * N_FEAT + f], ua);
      ub = fmaf(w_lds[0][j + 2], X[(size_t)(i0 + j + 2) * N_FEAT + f], ub);
    }
    for (; j < n; j += 2)
      ua = fmaf(w_lds[0][j], X[(size_t)(i0 + j) * N_FEAT + f], ua);
  } else {
    for (int j = jp; j < n; j += 2) {
      float wj = atomicAdd(&wbuf[i0 + j], 0.f);   // coherent read past L1
      ua = fmaf(wj, X[(size_t)(i0 + j) * N_FEAT + f], ua);
    }
  }
  red[jp][f] = ua + ub;
  __syncthreads();
  if (jp == 0) Us[f] = red[0][f] + red[1][f];
  __syncthreads();

  // ---- out[g][f] = sum_k u_k * Wv[k][f]  (2-way k-split) ----
  const int k0 = jp * 128;
  const float* wp = Wv + (size_t)k0 * N_FEAT + f;
  const float* us = &Us[k0];
  float a0 = 0.f, a1 = 0.f, a2 = 0.f, a3 = 0.f;
#pragma unroll 8
  for (int k = 0; k < 128; k += 4) {
    a0 = fmaf(us[k],     wp[(size_t)k * N_FEAT], a0);
    a1 = fmaf(us[k + 1], wp[(size_t)(k + 1) * N_FEAT], a1);
    a2 = fmaf(us[k + 2], wp[(size_t)(k + 2) * N_FEAT], a2);
    a3 = fmaf(us[k + 3], wp[(size_t)(k + 3) * N_FEAT], a3);
  }
  __syncthreads();
  red[jp][f] = (a0 + a1) + (a2 + a3);
  __syncthreads();
  if (jp == 0) out[g * N_FEAT + f] = red[0][f] + red[1][f];
}

// ---------------------------------------------------------------------------
extern "C" void kernel_launch(void* const* d_in, const int* in_sizes, int n_in,
                              void* d_out, int out_size, void* d_ws, size_t ws_size,
                              hipStream_t stream) {
  const float* X     = (const float*)d_in[0];
  const int*   batch = (const int*)d_in[1];
  const float* Wq    = (const float*)d_in[2];
  const float* Wk    = (const float*)d_in[3];
  const float* Wv    = (const float*)d_in[4];
  float* out = (float*)d_out;

  char* ws = (char*)d_ws;
  int*      starts = (int*)(ws + WS_STARTS);
  float*    wbuf   = (float*)(ws + WS_WBUF);
  unsigned* Qb     = (unsigned*)(ws + WS_QB);
  unsigned* Kb     = (unsigned*)(ws + WS_KB);
  unsigned* Wt     = (unsigned*)(ws + WS_WT);

  wt_prep_k<<<256, 64, 0, stream>>>(Wq, Wk, batch, Wt, starts);
  qk_proj_k<<<N_NODES / 16, 256, 0, stream>>>(X, Wt, Qb, Kb);
  attn_pool_k<<<N_GRAPHS, 512, 0, stream>>>(X, starts, Qb, Kb, Wv, out, wbuf);
}